// Round 5
// baseline (56.827 us; speedup 1.0000x reference)
//
#include <hip/hip_runtime.h>
#include <math.h>

constexpr int NPTS = 1024;
constexpr int WPB = 4;   // waves (batches) per block in the reduce phase

// fast HW approximations (v_rcp_f32 / v_rsq_f32 / v_sqrt_f32, ~1ulp)
__device__ __forceinline__ float frcp(float x)  { return __builtin_amdgcn_rcpf(x); }
__device__ __forceinline__ float frsq(float x)  { return __builtin_amdgcn_rsqf(x); }
__device__ __forceinline__ float fsqrt(float x) { return __builtin_amdgcn_sqrtf(x); }

// 3x3 Kabsch solve from the 15 reduced sums; writes R (9) + t (3) for batch b
__device__ __forceinline__ void svd_solve(const float* __restrict__ ws,
                                          float* __restrict__ out,
                                          int b, int nbatch)
{
    const float4* w = (const float4*)(ws + (size_t)b * 16);
    float4 w0 = w[0], w1 = w[1], w2 = w[2], w3 = w[3];
    float r[15] = {w0.x, w0.y, w0.z, w0.w,
                   w1.x, w1.y, w1.z, w1.w,
                   w2.x, w2.y, w2.z, w2.w,
                   w3.x, w3.y, w3.z};

    const float invN = 1.0f / (float)NPTS;
    float mus[3] = {r[0] * invN, r[1] * invN, r[2] * invN};
    float mut[3] = {r[3] * invN, r[4] * invN, r[5] * invN};

    float H[3][3];
#pragma unroll
    for (int i = 0; i < 3; ++i)
#pragma unroll
        for (int j = 0; j < 3; ++j)
            H[i][j] = r[6 + i * 3 + j] - (float)NPTS * mus[i] * mut[j];

    // A = H^T H (symmetric PSD)
    float A[3][3];
#pragma unroll
    for (int i = 0; i < 3; ++i)
#pragma unroll
        for (int j = 0; j < 3; ++j)
            A[i][j] = H[0][i] * H[0][j] + H[1][i] * H[1][j] + H[2][i] * H[2][j];

    // cyclic Jacobi with HW-fast rcp/rsq/sqrt
    float V[3][3] = {{1.f, 0.f, 0.f}, {0.f, 1.f, 0.f}, {0.f, 0.f, 1.f}};
    auto rot = [&](int p, int q) {
        float apq = A[p][q];
        float diff = A[q][q] - A[p][p];
        float theta = diff * frcp(2.0f * apq);
        float t = copysignf(frcp(fabsf(theta) + fsqrt(fmaf(theta, theta, 1.0f))), theta);
        t = (fabsf(apq) < 1e-20f) ? 0.0f : t;   // apq==0 -> identity rotation
        float c = frsq(fmaf(t, t, 1.0f));
        float s = t * c;
#pragma unroll
        for (int k = 0; k < 3; ++k) {
            float akp = A[k][p], akq = A[k][q];
            A[k][p] = c * akp - s * akq;
            A[k][q] = s * akp + c * akq;
        }
#pragma unroll
        for (int k = 0; k < 3; ++k) {
            float apk = A[p][k], aqk = A[q][k];
            A[p][k] = c * apk - s * aqk;
            A[q][k] = s * apk + c * aqk;
        }
#pragma unroll
        for (int k = 0; k < 3; ++k) {
            float vkp = V[k][p], vkq = V[k][q];
            V[k][p] = c * vkp - s * vkq;
            V[k][q] = s * vkp + c * vkq;
        }
    };
#pragma unroll
    for (int sweep = 0; sweep < 5; ++sweep) {
        rot(0, 1);
        rot(0, 2);
        rot(1, 2);
    }

    // branchless descending sort of eigenpairs
    float l0 = A[0][0], l1 = A[1][1], l2 = A[2][2];
    float e0[3] = {V[0][0], V[1][0], V[2][0]};
    float e1[3] = {V[0][1], V[1][1], V[2][1]};
    float e2[3] = {V[0][2], V[1][2], V[2][2]};
    auto cswap = [](float& la, float* va, float& lb, float* vb) {
        bool sw = lb > la;
        float tl = sw ? lb : la;
        lb = sw ? la : lb;
        la = tl;
#pragma unroll
        for (int k = 0; k < 3; ++k) {
            float tv = sw ? vb[k] : va[k];
            vb[k] = sw ? va[k] : vb[k];
            va[k] = tv;
        }
    };
    cswap(l0, e0, l1, e1);
    cswap(l0, e0, l2, e2);
    cswap(l1, e1, l2, e2);

    float *v1 = e0, *v2 = e1, *v3 = e2;

    // u1 = norm(H v1); u2 = GramSchmidt(H v2); u3 = u1 x u2  (det U = +1)
    float u1[3], u2[3], u3[3], hv[3];
    hv[0] = H[0][0]*v1[0] + H[0][1]*v1[1] + H[0][2]*v1[2];
    hv[1] = H[1][0]*v1[0] + H[1][1]*v1[1] + H[1][2]*v1[2];
    hv[2] = H[2][0]*v1[0] + H[2][1]*v1[1] + H[2][2]*v1[2];
    {
        float n = frsq(fmaf(hv[0], hv[0], fmaf(hv[1], hv[1], hv[2]*hv[2])) + 1e-30f);
        u1[0] = hv[0] * n; u1[1] = hv[1] * n; u1[2] = hv[2] * n;
    }
    hv[0] = H[0][0]*v2[0] + H[0][1]*v2[1] + H[0][2]*v2[2];
    hv[1] = H[1][0]*v2[0] + H[1][1]*v2[1] + H[1][2]*v2[2];
    hv[2] = H[2][0]*v2[0] + H[2][1]*v2[1] + H[2][2]*v2[2];
    {
        float d = u1[0]*hv[0] + u1[1]*hv[1] + u1[2]*hv[2];
        hv[0] -= d * u1[0]; hv[1] -= d * u1[1]; hv[2] -= d * u1[2];
        float n = frsq(fmaf(hv[0], hv[0], fmaf(hv[1], hv[1], hv[2]*hv[2])) + 1e-30f);
        u2[0] = hv[0] * n; u2[1] = hv[1] * n; u2[2] = hv[2] * n;
    }
    u3[0] = u1[1]*u2[2] - u1[2]*u2[1];
    u3[1] = u1[2]*u2[0] - u1[0]*u2[2];
    u3[2] = u1[0]*u2[1] - u1[1]*u2[0];

    // R = v1 u1^T + v2 u2^T + det(V) * v3 u3^T
    float cx = v1[1]*v2[2] - v1[2]*v2[1];
    float cy = v1[2]*v2[0] - v1[0]*v2[2];
    float cz = v1[0]*v2[1] - v1[1]*v2[0];
    float detV = cx * v3[0] + cy * v3[1] + cz * v3[2];
    float d3 = (detV < 0.f) ? -1.f : 1.f;

    float R[3][3];
#pragma unroll
    for (int i = 0; i < 3; ++i)
#pragma unroll
        for (int j = 0; j < 3; ++j)
            R[i][j] = v1[i]*u1[j] + v2[i]*u2[j] + d3 * v3[i]*u3[j];

    float tvec[3];
#pragma unroll
    for (int i = 0; i < 3; ++i)
        tvec[i] = mut[i] - (R[i][0]*mus[0] + R[i][1]*mus[1] + R[i][2]*mus[2]);

    float* Rout = out + (size_t)b * 9;
#pragma unroll
    for (int i = 0; i < 3; ++i)
#pragma unroll
        for (int j = 0; j < 3; ++j)
            Rout[i * 3 + j] = R[i][j];
    float* tout = out + (size_t)nbatch * 9 + (size_t)b * 3;
#pragma unroll
    for (int i = 0; i < 3; ++i) tout[i] = tvec[i];
}

// Fused: wave-per-batch reduction; last-arriving blocks run the lane-parallel
// SVDs (no second dispatch). All blocks are co-resident (4/CU) -> no deadlock.
__global__ __launch_bounds__(256) void kabsch_fused(
    const float* __restrict__ src, const float* __restrict__ tgt,
    float* __restrict__ ws, unsigned* __restrict__ cnt,
    float* __restrict__ out, int nbatch, int nblocks, int cons_threshold)
{
    const int wave = threadIdx.x >> 6;
    const int lane = threadIdx.x & 63;
    const int b = blockIdx.x * WPB + wave;

    float acc[15];
#pragma unroll
    for (int i = 0; i < 15; ++i) acc[i] = 0.f;

    if (b < nbatch) {
        const size_t base = (size_t)b * (NPTS * 3);
#pragma unroll
        for (int j = 0; j < 4; ++j) {
            const int g = j * 64 + lane;
            const float* sp = src + base + g * 12;
            const float* tp = tgt + base + g * 12;
            float4 sA = *(const float4*)(sp + 0);
            float4 sB = *(const float4*)(sp + 4);
            float4 sC = *(const float4*)(sp + 8);
            float4 tA = *(const float4*)(tp + 0);
            float4 tB = *(const float4*)(tp + 4);
            float4 tC = *(const float4*)(tp + 8);

            float sx[4] = {sA.x, sA.w, sB.z, sC.y};
            float sy[4] = {sA.y, sB.x, sB.w, sC.z};
            float sz[4] = {sA.z, sB.y, sC.x, sC.w};
            float tx[4] = {tA.x, tA.w, tB.z, tC.y};
            float ty[4] = {tA.y, tB.x, tB.w, tC.z};
            float tz[4] = {tA.z, tB.y, tC.x, tC.w};

#pragma unroll
            for (int k = 0; k < 4; ++k) {
                acc[0] += sx[k]; acc[1] += sy[k]; acc[2] += sz[k];
                acc[3] += tx[k]; acc[4] += ty[k]; acc[5] += tz[k];
                acc[6]  += sx[k] * tx[k]; acc[7]  += sx[k] * ty[k]; acc[8]  += sx[k] * tz[k];
                acc[9]  += sy[k] * tx[k]; acc[10] += sy[k] * ty[k]; acc[11] += sy[k] * tz[k];
                acc[12] += sz[k] * tx[k]; acc[13] += sz[k] * ty[k]; acc[14] += sz[k] * tz[k];
            }
        }
    }

#pragma unroll
    for (int off = 32; off >= 1; off >>= 1) {
#pragma unroll
        for (int i = 0; i < 15; ++i)
            acc[i] += __shfl_down(acc[i], off, 64);
    }

    if (b < nbatch && lane == 0) {
        float4* w = (float4*)(ws + (size_t)b * 16);
        w[0] = make_float4(acc[0],  acc[1],  acc[2],  acc[3]);
        w[1] = make_float4(acc[4],  acc[5],  acc[6],  acc[7]);
        w[2] = make_float4(acc[8],  acc[9],  acc[10], acc[11]);
        w[3] = make_float4(acc[12], acc[13], acc[14], 0.f);
    }

    // ----- arrive (release): all this block's ws stores happen-before the add
    __shared__ unsigned s_old;
    __syncthreads();
    if (threadIdx.x == 0) {
        s_old = __hip_atomic_fetch_add(cnt, 1u, __ATOMIC_RELEASE,
                                       __HIP_MEMORY_SCOPE_AGENT);
    }
    __syncthreads();
    const unsigned old = s_old;
    if ((int)old < cons_threshold) return;   // not a consumer block

    // ----- wait (acquire) until every block has arrived
    if (threadIdx.x == 0) {
        while (__hip_atomic_load(cnt, __ATOMIC_ACQUIRE,
                                 __HIP_MEMORY_SCOPE_AGENT) < (unsigned)nblocks)
            __builtin_amdgcn_s_sleep(2);
    }
    __syncthreads();

    const int chunk = (int)old - cons_threshold;
    const int sb = chunk * 256 + threadIdx.x;
    if (sb < nbatch)
        svd_solve(ws, out, sb, nbatch);
}

extern "C" void kernel_launch(void* const* d_in, const int* in_sizes, int n_in,
                              void* d_out, int out_size, void* d_ws, size_t ws_size,
                              hipStream_t stream) {
    const float* src = (const float*)d_in[0];
    const float* tgt = (const float*)d_in[1];
    float* out = (float*)d_out;
    float* ws = (float*)d_ws;
    const int nbatch = in_sizes[0] / (NPTS * 3);

    unsigned* cnt = (unsigned*)(ws + (size_t)nbatch * 16);   // after the sums
    hipMemsetAsync(cnt, 0, sizeof(unsigned), stream);        // graph memset node

    const int nblocks = (nbatch + WPB - 1) / WPB;
    const int ncons = (nbatch + 255) / 256;                  // consumer blocks
    const int cons_threshold = nblocks - ncons;
    kabsch_fused<<<nblocks, 256, 0, stream>>>(src, tgt, ws, cnt, out,
                                              nbatch, nblocks, cons_threshold);
}

// Round 6
// 24.748 us; speedup vs baseline: 2.2962x; 2.2962x over previous
//
#include <hip/hip_runtime.h>
#include <math.h>

constexpr int NPTS = 1024;
constexpr int WPB = 4;   // waves (batches) per block in the reduce phase

// ---------------- Phase A: per-batch 15-sum reduction (memory-bound) -------
// Each wave owns one batch (1024 pts); each lane 16 pts = 24 float4 loads,
// ALL issued before any compute so ~24 loads/lane stay in flight.
__global__ __launch_bounds__(256, 4) void reduce_kernel(
    const float* __restrict__ src, const float* __restrict__ tgt,
    float* __restrict__ ws, int nbatch)
{
    const int wave = threadIdx.x >> 6;
    const int lane = threadIdx.x & 63;
    const int b = blockIdx.x * WPB + wave;
    if (b >= nbatch) return;

    const size_t base = (size_t)b * (NPTS * 3);
    const float* sp0 = src + base + lane * 12;
    const float* tp0 = tgt + base + lane * 12;

    float4 sv[12], tv[12];
#pragma unroll
    for (int j = 0; j < 4; ++j) {
        const float* sp = sp0 + j * (64 * 12);
        const float* tp = tp0 + j * (64 * 12);
        sv[j * 3 + 0] = *(const float4*)(sp + 0);
        sv[j * 3 + 1] = *(const float4*)(sp + 4);
        sv[j * 3 + 2] = *(const float4*)(sp + 8);
        tv[j * 3 + 0] = *(const float4*)(tp + 0);
        tv[j * 3 + 1] = *(const float4*)(tp + 4);
        tv[j * 3 + 2] = *(const float4*)(tp + 8);
    }

    float acc[15];
#pragma unroll
    for (int i = 0; i < 15; ++i) acc[i] = 0.f;

#pragma unroll
    for (int j = 0; j < 4; ++j) {
        float4 sA = sv[j * 3 + 0], sB = sv[j * 3 + 1], sC = sv[j * 3 + 2];
        float4 tA = tv[j * 3 + 0], tB = tv[j * 3 + 1], tC = tv[j * 3 + 2];

        float sx[4] = {sA.x, sA.w, sB.z, sC.y};
        float sy[4] = {sA.y, sB.x, sB.w, sC.z};
        float sz[4] = {sA.z, sB.y, sC.x, sC.w};
        float tx[4] = {tA.x, tA.w, tB.z, tC.y};
        float ty[4] = {tA.y, tB.x, tB.w, tC.z};
        float tz[4] = {tA.z, tB.y, tC.x, tC.w};

#pragma unroll
        for (int k = 0; k < 4; ++k) {
            acc[0] += sx[k]; acc[1] += sy[k]; acc[2] += sz[k];
            acc[3] += tx[k]; acc[4] += ty[k]; acc[5] += tz[k];
            acc[6]  += sx[k] * tx[k]; acc[7]  += sx[k] * ty[k]; acc[8]  += sx[k] * tz[k];
            acc[9]  += sy[k] * tx[k]; acc[10] += sy[k] * ty[k]; acc[11] += sy[k] * tz[k];
            acc[12] += sz[k] * tx[k]; acc[13] += sz[k] * ty[k]; acc[14] += sz[k] * tz[k];
        }
    }

#pragma unroll
    for (int off = 32; off >= 1; off >>= 1) {
#pragma unroll
        for (int i = 0; i < 15; ++i)
            acc[i] += __shfl_down(acc[i], off, 64);
    }

    if (lane == 0) {
        float4* w = (float4*)(ws + (size_t)b * 16);
        w[0] = make_float4(acc[0],  acc[1],  acc[2],  acc[3]);
        w[1] = make_float4(acc[4],  acc[5],  acc[6],  acc[7]);
        w[2] = make_float4(acc[8],  acc[9],  acc[10], acc[11]);
        w[3] = make_float4(acc[12], acc[13], acc[14], 0.f);
    }
}

// fast HW approximations (v_rcp_f32 / v_rsq_f32 / v_sqrt_f32, ~1ulp)
__device__ __forceinline__ float frcp(float x)  { return __builtin_amdgcn_rcpf(x); }
__device__ __forceinline__ float frsq(float x)  { return __builtin_amdgcn_rsqf(x); }
__device__ __forceinline__ float fsqrt(float x) { return __builtin_amdgcn_sqrtf(x); }

// ---------------- Phase B: one 3x3 SVD per LANE (latency-bound chain) ------
__global__ __launch_bounds__(256) void svd_kernel(
    const float* __restrict__ ws, float* __restrict__ out, int nbatch)
{
    const int b = blockIdx.x * 256 + threadIdx.x;
    if (b >= nbatch) return;

    const float4* w = (const float4*)(ws + (size_t)b * 16);
    float4 w0 = w[0], w1 = w[1], w2 = w[2], w3 = w[3];
    float r[15] = {w0.x, w0.y, w0.z, w0.w,
                   w1.x, w1.y, w1.z, w1.w,
                   w2.x, w2.y, w2.z, w2.w,
                   w3.x, w3.y, w3.z};

    const float invN = 1.0f / (float)NPTS;
    float mus[3] = {r[0] * invN, r[1] * invN, r[2] * invN};
    float mut[3] = {r[3] * invN, r[4] * invN, r[5] * invN};

    float H[3][3];
#pragma unroll
    for (int i = 0; i < 3; ++i)
#pragma unroll
        for (int j = 0; j < 3; ++j)
            H[i][j] = r[6 + i * 3 + j] - (float)NPTS * mus[i] * mut[j];

    // A = H^T H (symmetric PSD)
    float A[3][3];
#pragma unroll
    for (int i = 0; i < 3; ++i)
#pragma unroll
        for (int j = 0; j < 3; ++j)
            A[i][j] = H[0][i] * H[0][j] + H[1][i] * H[1][j] + H[2][i] * H[2][j];

    // cyclic Jacobi with HW-fast rcp/rsq/sqrt (short dependent chain)
    float V[3][3] = {{1.f, 0.f, 0.f}, {0.f, 1.f, 0.f}, {0.f, 0.f, 1.f}};
    auto rot = [&](int p, int q) {
        float apq = A[p][q];
        float diff = A[q][q] - A[p][p];
        float theta = diff * frcp(2.0f * apq);
        float t = copysignf(frcp(fabsf(theta) + fsqrt(fmaf(theta, theta, 1.0f))), theta);
        t = (fabsf(apq) < 1e-20f) ? 0.0f : t;   // apq==0 -> identity rotation
        float c = frsq(fmaf(t, t, 1.0f));
        float s = t * c;
#pragma unroll
        for (int k = 0; k < 3; ++k) {
            float akp = A[k][p], akq = A[k][q];
            A[k][p] = c * akp - s * akq;
            A[k][q] = s * akp + c * akq;
        }
#pragma unroll
        for (int k = 0; k < 3; ++k) {
            float apk = A[p][k], aqk = A[q][k];
            A[p][k] = c * apk - s * aqk;
            A[q][k] = s * apk + c * aqk;
        }
#pragma unroll
        for (int k = 0; k < 3; ++k) {
            float vkp = V[k][p], vkq = V[k][q];
            V[k][p] = c * vkp - s * vkq;
            V[k][q] = s * vkp + c * vkq;
        }
    };
#pragma unroll
    for (int sweep = 0; sweep < 4; ++sweep) {
        rot(0, 1);
        rot(0, 2);
        rot(1, 2);
    }

    // branchless descending sort of eigenpairs
    float l0 = A[0][0], l1 = A[1][1], l2 = A[2][2];
    float e0[3] = {V[0][0], V[1][0], V[2][0]};
    float e1[3] = {V[0][1], V[1][1], V[2][1]};
    float e2[3] = {V[0][2], V[1][2], V[2][2]};
    auto cswap = [](float& la, float* va, float& lb, float* vb) {
        bool sw = lb > la;
        float tl = sw ? lb : la;
        lb = sw ? la : lb;
        la = tl;
#pragma unroll
        for (int k = 0; k < 3; ++k) {
            float tv2 = sw ? vb[k] : va[k];
            vb[k] = sw ? va[k] : vb[k];
            va[k] = tv2;
        }
    };
    cswap(l0, e0, l1, e1);
    cswap(l0, e0, l2, e2);
    cswap(l1, e1, l2, e2);

    float *v1 = e0, *v2 = e1, *v3 = e2;

    // u1 = norm(H v1); u2 = GramSchmidt(H v2); u3 = u1 x u2  (det U = +1)
    float u1[3], u2[3], u3[3], hv[3];
    hv[0] = H[0][0]*v1[0] + H[0][1]*v1[1] + H[0][2]*v1[2];
    hv[1] = H[1][0]*v1[0] + H[1][1]*v1[1] + H[1][2]*v1[2];
    hv[2] = H[2][0]*v1[0] + H[2][1]*v1[1] + H[2][2]*v1[2];
    {
        float n = frsq(fmaf(hv[0], hv[0], fmaf(hv[1], hv[1], hv[2]*hv[2])) + 1e-30f);
        u1[0] = hv[0] * n; u1[1] = hv[1] * n; u1[2] = hv[2] * n;
    }
    hv[0] = H[0][0]*v2[0] + H[0][1]*v2[1] + H[0][2]*v2[2];
    hv[1] = H[1][0]*v2[0] + H[1][1]*v2[1] + H[1][2]*v2[2];
    hv[2] = H[2][0]*v2[0] + H[2][1]*v2[1] + H[2][2]*v2[2];
    {
        float d = u1[0]*hv[0] + u1[1]*hv[1] + u1[2]*hv[2];
        hv[0] -= d * u1[0]; hv[1] -= d * u1[1]; hv[2] -= d * u1[2];
        float n = frsq(fmaf(hv[0], hv[0], fmaf(hv[1], hv[1], hv[2]*hv[2])) + 1e-30f);
        u2[0] = hv[0] * n; u2[1] = hv[1] * n; u2[2] = hv[2] * n;
    }
    u3[0] = u1[1]*u2[2] - u1[2]*u2[1];
    u3[1] = u1[2]*u2[0] - u1[0]*u2[2];
    u3[2] = u1[0]*u2[1] - u1[1]*u2[0];

    // R = v1 u1^T + v2 u2^T + det(V) * v3 u3^T
    float cx = v1[1]*v2[2] - v1[2]*v2[1];
    float cy = v1[2]*v2[0] - v1[0]*v2[2];
    float cz = v1[0]*v2[1] - v1[1]*v2[0];
    float detV = cx * v3[0] + cy * v3[1] + cz * v3[2];
    float d3 = (detV < 0.f) ? -1.f : 1.f;

    float R[3][3];
#pragma unroll
    for (int i = 0; i < 3; ++i)
#pragma unroll
        for (int j = 0; j < 3; ++j)
            R[i][j] = v1[i]*u1[j] + v2[i]*u2[j] + d3 * v3[i]*u3[j];

    float tvec[3];
#pragma unroll
    for (int i = 0; i < 3; ++i)
        tvec[i] = mut[i] - (R[i][0]*mus[0] + R[i][1]*mus[1] + R[i][2]*mus[2]);

    float* Rout = out + (size_t)b * 9;
#pragma unroll
    for (int i = 0; i < 3; ++i)
#pragma unroll
        for (int j = 0; j < 3; ++j)
            Rout[i * 3 + j] = R[i][j];
    float* tout = out + (size_t)nbatch * 9 + (size_t)b * 3;
#pragma unroll
    for (int i = 0; i < 3; ++i) tout[i] = tvec[i];
}

extern "C" void kernel_launch(void* const* d_in, const int* in_sizes, int n_in,
                              void* d_out, int out_size, void* d_ws, size_t ws_size,
                              hipStream_t stream) {
    const float* src = (const float*)d_in[0];
    const float* tgt = (const float*)d_in[1];
    float* out = (float*)d_out;
    float* ws = (float*)d_ws;
    const int nbatch = in_sizes[0] / (NPTS * 3);

    const int nblocksA = (nbatch + WPB - 1) / WPB;
    reduce_kernel<<<nblocksA, 256, 0, stream>>>(src, tgt, ws, nbatch);

    const int nblocksB = (nbatch + 255) / 256;
    svd_kernel<<<nblocksB, 256, 0, stream>>>(ws, out, nbatch);
}

// Round 7
// 24.390 us; speedup vs baseline: 2.3299x; 1.0147x over previous
//
#include <hip/hip_runtime.h>
#include <math.h>

constexpr int NPTS = 1024;
constexpr int WPB = 4;   // waves (batches) per block in the reduce phase

struct F3 { float x, y, z; };   // 12-byte point -> global_load_dwordx3, dense

// ---------------- Phase A: per-batch 15-sum reduction (memory-bound) -------
// Wave owns one batch. Lane loads point (k*64+lane) as a 12B dwordx3:
// inter-lane stride 12B = fully dense per instruction (768B/wave-op),
// unlike the previous 48B-stride float4 scheme (3x L1 transactions).
__global__ __launch_bounds__(256, 4) void reduce_kernel(
    const float* __restrict__ src, const float* __restrict__ tgt,
    float* __restrict__ ws, int nbatch)
{
    const int wave = threadIdx.x >> 6;
    const int lane = threadIdx.x & 63;
    const int b = blockIdx.x * WPB + wave;
    if (b >= nbatch) return;

    const size_t base = (size_t)b * (NPTS * 3);
    const F3* __restrict__ ps = (const F3*)(src + base);
    const F3* __restrict__ pt = (const F3*)(tgt + base);

    float acc[15];
#pragma unroll
    for (int i = 0; i < 15; ++i) acc[i] = 0.f;

#pragma unroll
    for (int k = 0; k < 16; ++k) {
        const int p = k * 64 + lane;
        F3 s = ps[p];
        F3 t = pt[p];
        acc[0] += s.x; acc[1] += s.y; acc[2] += s.z;
        acc[3] += t.x; acc[4] += t.y; acc[5] += t.z;
        acc[6]  += s.x * t.x; acc[7]  += s.x * t.y; acc[8]  += s.x * t.z;
        acc[9]  += s.y * t.x; acc[10] += s.y * t.y; acc[11] += s.y * t.z;
        acc[12] += s.z * t.x; acc[13] += s.z * t.y; acc[14] += s.z * t.z;
    }

#pragma unroll
    for (int off = 32; off >= 1; off >>= 1) {
#pragma unroll
        for (int i = 0; i < 15; ++i)
            acc[i] += __shfl_down(acc[i], off, 64);
    }

    if (lane == 0) {
        float4* w = (float4*)(ws + (size_t)b * 16);
        w[0] = make_float4(acc[0],  acc[1],  acc[2],  acc[3]);
        w[1] = make_float4(acc[4],  acc[5],  acc[6],  acc[7]);
        w[2] = make_float4(acc[8],  acc[9],  acc[10], acc[11]);
        w[3] = make_float4(acc[12], acc[13], acc[14], 0.f);
    }
}

// fast HW approximations (v_rcp_f32 / v_rsq_f32 / v_sqrt_f32, ~1ulp)
__device__ __forceinline__ float frcp(float x)  { return __builtin_amdgcn_rcpf(x); }
__device__ __forceinline__ float frsq(float x)  { return __builtin_amdgcn_rsqf(x); }
__device__ __forceinline__ float fsqrt(float x) { return __builtin_amdgcn_sqrtf(x); }

// ---------------- Phase B: one 3x3 SVD per LANE (latency-bound chain) ------
__global__ __launch_bounds__(256) void svd_kernel(
    const float* __restrict__ ws, float* __restrict__ out, int nbatch)
{
    const int b = blockIdx.x * 256 + threadIdx.x;
    if (b >= nbatch) return;

    const float4* w = (const float4*)(ws + (size_t)b * 16);
    float4 w0 = w[0], w1 = w[1], w2 = w[2], w3 = w[3];
    float r[15] = {w0.x, w0.y, w0.z, w0.w,
                   w1.x, w1.y, w1.z, w1.w,
                   w2.x, w2.y, w2.z, w2.w,
                   w3.x, w3.y, w3.z};

    const float invN = 1.0f / (float)NPTS;
    float mus[3] = {r[0] * invN, r[1] * invN, r[2] * invN};
    float mut[3] = {r[3] * invN, r[4] * invN, r[5] * invN};

    float H[3][3];
#pragma unroll
    for (int i = 0; i < 3; ++i)
#pragma unroll
        for (int j = 0; j < 3; ++j)
            H[i][j] = r[6 + i * 3 + j] - (float)NPTS * mus[i] * mut[j];

    // A = H^T H (symmetric PSD)
    float A[3][3];
#pragma unroll
    for (int i = 0; i < 3; ++i)
#pragma unroll
        for (int j = 0; j < 3; ++j)
            A[i][j] = H[0][i] * H[0][j] + H[1][i] * H[1][j] + H[2][i] * H[2][j];

    // cyclic Jacobi with HW-fast rcp/rsq/sqrt (short dependent chain)
    float V[3][3] = {{1.f, 0.f, 0.f}, {0.f, 1.f, 0.f}, {0.f, 0.f, 1.f}};
    auto rot = [&](int p, int q) {
        float apq = A[p][q];
        float diff = A[q][q] - A[p][p];
        float theta = diff * frcp(2.0f * apq);
        float t = copysignf(frcp(fabsf(theta) + fsqrt(fmaf(theta, theta, 1.0f))), theta);
        t = (fabsf(apq) < 1e-20f) ? 0.0f : t;   // apq==0 -> identity rotation
        float c = frsq(fmaf(t, t, 1.0f));
        float s = t * c;
#pragma unroll
        for (int k = 0; k < 3; ++k) {
            float akp = A[k][p], akq = A[k][q];
            A[k][p] = c * akp - s * akq;
            A[k][q] = s * akp + c * akq;
        }
#pragma unroll
        for (int k = 0; k < 3; ++k) {
            float apk = A[p][k], aqk = A[q][k];
            A[p][k] = c * apk - s * aqk;
            A[q][k] = s * apk + c * aqk;
        }
#pragma unroll
        for (int k = 0; k < 3; ++k) {
            float vkp = V[k][p], vkq = V[k][q];
            V[k][p] = c * vkp - s * vkq;
            V[k][q] = s * vkp + c * vkq;
        }
    };
#pragma unroll
    for (int sweep = 0; sweep < 4; ++sweep) {
        rot(0, 1);
        rot(0, 2);
        rot(1, 2);
    }

    // branchless descending sort of eigenpairs
    float l0 = A[0][0], l1 = A[1][1], l2 = A[2][2];
    float e0[3] = {V[0][0], V[1][0], V[2][0]};
    float e1[3] = {V[0][1], V[1][1], V[2][1]};
    float e2[3] = {V[0][2], V[1][2], V[2][2]};
    auto cswap = [](float& la, float* va, float& lb, float* vb) {
        bool sw = lb > la;
        float tl = sw ? lb : la;
        lb = sw ? la : lb;
        la = tl;
#pragma unroll
        for (int k = 0; k < 3; ++k) {
            float tv2 = sw ? vb[k] : va[k];
            vb[k] = sw ? va[k] : vb[k];
            va[k] = tv2;
        }
    };
    cswap(l0, e0, l1, e1);
    cswap(l0, e0, l2, e2);
    cswap(l1, e1, l2, e2);

    float *v1 = e0, *v2 = e1, *v3 = e2;

    // u1 = norm(H v1); u2 = GramSchmidt(H v2); u3 = u1 x u2  (det U = +1)
    float u1[3], u2[3], u3[3], hv[3];
    hv[0] = H[0][0]*v1[0] + H[0][1]*v1[1] + H[0][2]*v1[2];
    hv[1] = H[1][0]*v1[0] + H[1][1]*v1[1] + H[1][2]*v1[2];
    hv[2] = H[2][0]*v1[0] + H[2][1]*v1[1] + H[2][2]*v1[2];
    {
        float n = frsq(fmaf(hv[0], hv[0], fmaf(hv[1], hv[1], hv[2]*hv[2])) + 1e-30f);
        u1[0] = hv[0] * n; u1[1] = hv[1] * n; u1[2] = hv[2] * n;
    }
    hv[0] = H[0][0]*v2[0] + H[0][1]*v2[1] + H[0][2]*v2[2];
    hv[1] = H[1][0]*v2[0] + H[1][1]*v2[1] + H[1][2]*v2[2];
    hv[2] = H[2][0]*v2[0] + H[2][1]*v2[1] + H[2][2]*v2[2];
    {
        float d = u1[0]*hv[0] + u1[1]*hv[1] + u1[2]*hv[2];
        hv[0] -= d * u1[0]; hv[1] -= d * u1[1]; hv[2] -= d * u1[2];
        float n = frsq(fmaf(hv[0], hv[0], fmaf(hv[1], hv[1], hv[2]*hv[2])) + 1e-30f);
        u2[0] = hv[0] * n; u2[1] = hv[1] * n; u2[2] = hv[2] * n;
    }
    u3[0] = u1[1]*u2[2] - u1[2]*u2[1];
    u3[1] = u1[2]*u2[0] - u1[0]*u2[2];
    u3[2] = u1[0]*u2[1] - u1[1]*u2[0];

    // R = v1 u1^T + v2 u2^T + det(V) * v3 u3^T
    float cx = v1[1]*v2[2] - v1[2]*v2[1];
    float cy = v1[2]*v2[0] - v1[0]*v2[2];
    float cz = v1[0]*v2[1] - v1[1]*v2[0];
    float detV = cx * v3[0] + cy * v3[1] + cz * v3[2];
    float d3 = (detV < 0.f) ? -1.f : 1.f;

    float R[3][3];
#pragma unroll
    for (int i = 0; i < 3; ++i)
#pragma unroll
        for (int j = 0; j < 3; ++j)
            R[i][j] = v1[i]*u1[j] + v2[i]*u2[j] + d3 * v3[i]*u3[j];

    float tvec[3];
#pragma unroll
    for (int i = 0; i < 3; ++i)
        tvec[i] = mut[i] - (R[i][0]*mus[0] + R[i][1]*mus[1] + R[i][2]*mus[2]);

    float* Rout = out + (size_t)b * 9;
#pragma unroll
    for (int i = 0; i < 3; ++i)
#pragma unroll
        for (int j = 0; j < 3; ++j)
            Rout[i * 3 + j] = R[i][j];
    float* tout = out + (size_t)nbatch * 9 + (size_t)b * 3;
#pragma unroll
    for (int i = 0; i < 3; ++i) tout[i] = tvec[i];
}

extern "C" void kernel_launch(void* const* d_in, const int* in_sizes, int n_in,
                              void* d_out, int out_size, void* d_ws, size_t ws_size,
                              hipStream_t stream) {
    const float* src = (const float*)d_in[0];
    const float* tgt = (const float*)d_in[1];
    float* out = (float*)d_out;
    float* ws = (float*)d_ws;
    const int nbatch = in_sizes[0] / (NPTS * 3);

    const int nblocksA = (nbatch + WPB - 1) / WPB;
    reduce_kernel<<<nblocksA, 256, 0, stream>>>(src, tgt, ws, nbatch);

    const int nblocksB = (nbatch + 255) / 256;
    svd_kernel<<<nblocksB, 256, 0, stream>>>(ws, out, nbatch);
}